// Round 8
// baseline (244.685 us; speedup 1.0000x reference)
//
#include <hip/hip_runtime.h>
#include <math.h>

#define TPB 256
#define NPTS 1024

// One Jacobi rotation on symmetric 3x3 'a' (zeroing a[P][Q]), accumulating
// eigenvectors into columns of V. All indices template-constant so the
// matrices live entirely in registers (no scratch).
template<int P, int Q, int R>
__device__ __forceinline__ void jrot(float a[3][3], float V[3][3]) {
  float apq = a[P][Q];
  if (fabsf(apq) < 1e-30f) return;
  float theta = (a[Q][Q] - a[P][P]) / (2.0f * apq);
  float t = copysignf(1.0f, theta) / (fabsf(theta) + sqrtf(theta * theta + 1.0f));
  float c = 1.0f / sqrtf(t * t + 1.0f);
  float s = t * c;
  float app = a[P][P], aqq = a[Q][Q];
  a[P][P] = app - t * apq;
  a[Q][Q] = aqq + t * apq;
  a[P][Q] = 0.0f; a[Q][P] = 0.0f;
  float arp = a[R][P], arq = a[R][Q];
  a[R][P] = c * arp - s * arq; a[P][R] = a[R][P];
  a[R][Q] = s * arp + c * arq; a[Q][R] = a[R][Q];
#pragma unroll
  for (int i = 0; i < 3; ++i) {
    float vip = V[i][P], viq = V[i][Q];
    V[i][P] = c * vip - s * viq;
    V[i][Q] = s * vip + c * viq;
  }
}

#define CSWAP(I, J)                                                        \
  if (ev[I] < ev[J]) {                                                     \
    float e_ = ev[I]; ev[I] = ev[J]; ev[J] = e_;                           \
    _Pragma("unroll")                                                      \
    for (int r2_ = 0; r2_ < 3; ++r2_) {                                    \
      float v_ = V[r2_][I]; V[r2_][I] = V[r2_][J]; V[r2_][J] = v_;         \
    }                                                                      \
  }

// From the 16 reduced sums r[] produce the 4x4 transform at 'o'.
__device__ __forceinline__ void svd_tail_write(const float r[16], float* o) {
  const float S = r[0];
  const float inv = 1.0f / (S + 1e-5f);
  const float sc[3] = {r[1] * inv, r[2] * inv, r[3] * inv};
  const float tc[3] = {r[4] * inv, r[5] * inv, r[6] * inv};
  const float f = 2.0f - S * inv;  // exact eps correction factor

  float H[3][3];
#pragma unroll
  for (int c = 0; c < 3; ++c)
#pragma unroll
    for (int d = 0; d < 3; ++d)
      H[c][d] = r[7 + 3 * c + d] * inv - sc[c] * tc[d] * f;

  // 3x3 SVD via Jacobi eigendecomposition of H^T H
  float Bm[3][3];
#pragma unroll
  for (int i = 0; i < 3; ++i)
#pragma unroll
    for (int j = 0; j < 3; ++j)
      Bm[i][j] = H[0][i] * H[0][j] + H[1][i] * H[1][j] + H[2][i] * H[2][j];

  float V[3][3] = {{1, 0, 0}, {0, 1, 0}, {0, 0, 1}};
  for (int sweep = 0; sweep < 8; ++sweep) {
    jrot<0, 1, 2>(Bm, V);
    jrot<0, 2, 1>(Bm, V);
    jrot<1, 2, 0>(Bm, V);
  }
  float ev[3] = {Bm[0][0], Bm[1][1], Bm[2][2]};
  CSWAP(0, 1)
  CSWAP(1, 2)
  CSWAP(0, 1)  // columns of V sorted by descending eigenvalue

  // U columns: U0 = H V0 / |.|, U1 = GS(H V1), U2 = U0 x U1 (det U = +1)
  float U[3][3];
  float w0[3], w1[3];
#pragma unroll
  for (int i = 0; i < 3; ++i)
    w0[i] = H[i][0] * V[0][0] + H[i][1] * V[1][0] + H[i][2] * V[2][0];
  float n0 = sqrtf(w0[0] * w0[0] + w0[1] * w0[1] + w0[2] * w0[2]);
  float in0 = (n0 > 1e-20f) ? 1.0f / n0 : 0.0f;
#pragma unroll
  for (int i = 0; i < 3; ++i) U[i][0] = w0[i] * in0;

#pragma unroll
  for (int i = 0; i < 3; ++i)
    w1[i] = H[i][0] * V[0][1] + H[i][1] * V[1][1] + H[i][2] * V[2][1];
  float d01 = U[0][0] * w1[0] + U[1][0] * w1[1] + U[2][0] * w1[2];
#pragma unroll
  for (int i = 0; i < 3; ++i) w1[i] -= d01 * U[i][0];
  float n1 = sqrtf(w1[0] * w1[0] + w1[1] * w1[1] + w1[2] * w1[2]);
  float in1 = (n1 > 1e-20f) ? 1.0f / n1 : 0.0f;
#pragma unroll
  for (int i = 0; i < 3; ++i) U[i][1] = w1[i] * in1;

  U[0][2] = U[1][0] * U[2][1] - U[2][0] * U[1][1];
  U[1][2] = U[2][0] * U[0][1] - U[0][0] * U[2][1];
  U[2][2] = U[0][0] * U[1][1] - U[1][0] * U[0][1];

  float detV = V[0][0] * (V[1][1] * V[2][2] - V[1][2] * V[2][1]) -
               V[0][1] * (V[1][0] * V[2][2] - V[1][2] * V[2][0]) +
               V[0][2] * (V[1][0] * V[2][1] - V[1][1] * V[2][0]);
  float s3 = (detV >= 0.0f) ? 1.0f : -1.0f;

  // R = V diag(1,1,s) U^T (invariant to eigencolumn sign choices)
  float R[3][3];
#pragma unroll
  for (int i = 0; i < 3; ++i)
#pragma unroll
    for (int j = 0; j < 3; ++j)
      R[i][j] = V[i][0] * U[j][0] + V[i][1] * U[j][1] + s3 * V[i][2] * U[j][2];

  float tr[3];
#pragma unroll
  for (int i = 0; i < 3; ++i)
    tr[i] = tc[i] - (R[i][0] * sc[0] + R[i][1] * sc[1] + R[i][2] * sc[2]);

  float4* o4 = (float4*)o;
  o4[0] = make_float4(R[0][0], R[0][1], R[0][2], tr[0]);
  o4[1] = make_float4(R[1][0], R[1][1], R[1][2], tr[1]);
  o4[2] = make_float4(R[2][0], R[2][1], R[2][2], tr[2]);
  o4[3] = make_float4(0.0f, 0.0f, 0.0f, 1.0f);
}

// Single fused kernel. One block per batch.
// Loads are wave-contiguous stride-1 float4 (1 KB/instr, perfectly
// coalesced — R7 showed 48B-lane-stride direct loads cost ~3x in the
// memory pipe). LDS round-trip is fully vectorized: 6 ds_write_b128 +
// 6 ds_read_b128 per thread (R2's 28 scalar LDS reads were the VALU
// cost). Weights load direct-to-register (already contiguous).
__global__ __launch_bounds__(TPB, 6) void wproc_fused(
    const float* __restrict__ src, const float* __restrict__ tgt,
    const float* __restrict__ wts, float* __restrict__ out) {
  const int b = blockIdx.x;
  const int t = threadIdx.x;
  const int lane = t & 63, wave = t >> 6;

  __shared__ float4 sh_src[NPTS * 3 / 4];  // 12 KiB
  __shared__ float4 sh_tgt[NPTS * 3 / 4];  // 12 KiB
  __shared__ float sh_fin[4][17];
  __shared__ float sh_r[16];
  // Partial-sum matrix UNIONed over sh_src's first 5 KiB — only touched
  // after a barrier that guarantees all sh_src reads are complete.
  float(*sh_part)[20] = (float(*)[20]) sh_src;  // 64 rows x 20 floats

  const float4* g_src = (const float4*)(src + (size_t)b * (NPTS * 3));
  const float4* g_tgt = (const float4*)(tgt + (size_t)b * (NPTS * 3));
  const float4* g_w   = (const float4*)(wts + (size_t)b * NPTS);

  // ---- Coalesced stage: 6 x (64 consecutive float4 per wave) ----
  const float4 a0 = g_src[t], a1 = g_src[t + 256], a2 = g_src[t + 512];
  const float4 c0 = g_tgt[t], c1 = g_tgt[t + 256], c2 = g_tgt[t + 512];
  const float4 w4 = g_w[t];  // weights for points 4t..4t+3, no staging
  sh_src[t] = a0; sh_src[t + 256] = a1; sh_src[t + 512] = a2;
  sh_tgt[t] = c0; sh_tgt[t + 256] = c1; sh_tgt[t + 512] = c2;
  __syncthreads();

  // ---- Own 4 points back as 3+3 vector reads (48B stride, <=4-way) ----
  const float4 s0 = sh_src[3 * t + 0], s1 = sh_src[3 * t + 1], s2 = sh_src[3 * t + 2];
  const float4 u0 = sh_tgt[3 * t + 0], u1 = sh_tgt[3 * t + 1], u2 = sh_tgt[3 * t + 2];

  // acc: [0]=Sw, [1..3]=Σw*src, [4..6]=Σw*tgt, [7..15]=Σw*src⊗tgt
  float acc[16];
#pragma unroll
  for (int k = 0; k < 16; ++k) acc[k] = 0.0f;

#define PT(W, SX, SY, SZ, TX, TY, TZ)                                   \
  {                                                                     \
    float wv = fmaxf((W), 0.0f); /* WEIGHT_THRESH = 0.0 */              \
    float wsx = wv * (SX), wsy = wv * (SY), wsz = wv * (SZ);            \
    acc[0] += wv;                                                       \
    acc[1] += wsx;       acc[2] += wsy;       acc[3] += wsz;            \
    acc[4] += wv * (TX); acc[5] += wv * (TY); acc[6] += wv * (TZ);      \
    acc[7]  += wsx * (TX); acc[8]  += wsx * (TY); acc[9]  += wsx * (TZ);\
    acc[10] += wsy * (TX); acc[11] += wsy * (TY); acc[12] += wsy * (TZ);\
    acc[13] += wsz * (TX); acc[14] += wsz * (TY); acc[15] += wsz * (TZ);\
  }

  PT(w4.x, s0.x, s0.y, s0.z, u0.x, u0.y, u0.z)
  PT(w4.y, s0.w, s1.x, s1.y, u0.w, u1.x, u1.y)
  PT(w4.z, s1.z, s1.w, s2.x, u1.z, u1.w, u2.x)
  PT(w4.w, s2.y, s2.z, s2.w, u2.y, u2.z, u2.w)
#undef PT

  // Two butterfly steps (32 shuffles), then LDS transpose reduction.
#pragma unroll
  for (int k = 0; k < 16; ++k) acc[k] += __shfl_down(acc[k], 32, 64);
#pragma unroll
  for (int k = 0; k < 16; ++k) acc[k] += __shfl_down(acc[k], 16, 64);

  __syncthreads();  // all sh_src reads done -> safe to alias as sh_part

  if (lane < 16) {  // lanes 0..15 hold sums over their 4-lane comb
    float4* pr = (float4*)&sh_part[wave * 16 + lane][0];
    pr[0] = make_float4(acc[0], acc[1], acc[2], acc[3]);
    pr[1] = make_float4(acc[4], acc[5], acc[6], acc[7]);
    pr[2] = make_float4(acc[8], acc[9], acc[10], acc[11]);
    pr[3] = make_float4(acc[12], acc[13], acc[14], acc[15]);
  }
  __syncthreads();

  // 64 threads: thread (g,k) sums component k over rows g*16..g*16+15.
  if (t < 64) {
    const int k = t & 15, g = t >> 4;
    float s = 0.0f;
#pragma unroll
    for (int j = 0; j < 16; ++j) s += sh_part[g * 16 + j][k];
    sh_fin[g][k] = s;
  }
  __syncthreads();

  if (t < 16)
    sh_r[t] = sh_fin[0][t] + sh_fin[1][t] + sh_fin[2][t] + sh_fin[3][t];
  __syncthreads();

  if (t != 0) return;
  float r[16];
#pragma unroll
  for (int k = 0; k < 16; ++k) r[k] = sh_r[k];
  svd_tail_write(r, out + (size_t)b * 16);
}

extern "C" void kernel_launch(void* const* d_in, const int* in_sizes, int n_in,
                              void* d_out, int out_size, void* d_ws, size_t ws_size,
                              hipStream_t stream) {
  const float* src = (const float*)d_in[0];
  const float* tgt = (const float*)d_in[1];
  const float* wts = (const float*)d_in[2];
  float* out = (float*)d_out;
  const int B = in_sizes[0] / (NPTS * 3);
  wproc_fused<<<dim3(B), dim3(TPB), 0, stream>>>(src, tgt, wts, out);
}

// Round 9
// 244.580 us; speedup vs baseline: 1.0004x; 1.0004x over previous
//
#include <hip/hip_runtime.h>
#include <math.h>

#define TPB 256
#define NPTS 1024

// One Jacobi rotation on symmetric 3x3 'a' (zeroing a[P][Q]), accumulating
// eigenvectors into columns of V. All indices template-constant so the
// matrices live entirely in registers (no scratch).
template<int P, int Q, int R>
__device__ __forceinline__ void jrot(float a[3][3], float V[3][3]) {
  float apq = a[P][Q];
  if (fabsf(apq) < 1e-30f) return;
  float theta = (a[Q][Q] - a[P][P]) / (2.0f * apq);
  float t = copysignf(1.0f, theta) / (fabsf(theta) + sqrtf(theta * theta + 1.0f));
  float c = 1.0f / sqrtf(t * t + 1.0f);
  float s = t * c;
  float app = a[P][P], aqq = a[Q][Q];
  a[P][P] = app - t * apq;
  a[Q][Q] = aqq + t * apq;
  a[P][Q] = 0.0f; a[Q][P] = 0.0f;
  float arp = a[R][P], arq = a[R][Q];
  a[R][P] = c * arp - s * arq; a[P][R] = a[R][P];
  a[R][Q] = s * arp + c * arq; a[Q][R] = a[R][Q];
#pragma unroll
  for (int i = 0; i < 3; ++i) {
    float vip = V[i][P], viq = V[i][Q];
    V[i][P] = c * vip - s * viq;
    V[i][Q] = s * vip + c * viq;
  }
}

#define CSWAP(I, J)                                                        \
  if (ev[I] < ev[J]) {                                                     \
    float e_ = ev[I]; ev[I] = ev[J]; ev[J] = e_;                           \
    _Pragma("unroll")                                                      \
    for (int r2_ = 0; r2_ < 3; ++r2_) {                                    \
      float v_ = V[r2_][I]; V[r2_][I] = V[r2_][J]; V[r2_][J] = v_;         \
    }                                                                      \
  }

// From the 16 reduced sums r[] produce the 4x4 transform at 'o'.
__device__ __forceinline__ void svd_tail_write(const float r[16], float* o) {
  const float S = r[0];
  const float inv = 1.0f / (S + 1e-5f);
  const float sc[3] = {r[1] * inv, r[2] * inv, r[3] * inv};
  const float tc[3] = {r[4] * inv, r[5] * inv, r[6] * inv};
  const float f = 2.0f - S * inv;  // exact eps correction factor

  float H[3][3];
#pragma unroll
  for (int c = 0; c < 3; ++c)
#pragma unroll
    for (int d = 0; d < 3; ++d)
      H[c][d] = r[7 + 3 * c + d] * inv - sc[c] * tc[d] * f;

  // 3x3 SVD via Jacobi eigendecomposition of H^T H
  float Bm[3][3];
#pragma unroll
  for (int i = 0; i < 3; ++i)
#pragma unroll
    for (int j = 0; j < 3; ++j)
      Bm[i][j] = H[0][i] * H[0][j] + H[1][i] * H[1][j] + H[2][i] * H[2][j];

  float V[3][3] = {{1, 0, 0}, {0, 1, 0}, {0, 0, 1}};
  for (int sweep = 0; sweep < 8; ++sweep) {
    jrot<0, 1, 2>(Bm, V);
    jrot<0, 2, 1>(Bm, V);
    jrot<1, 2, 0>(Bm, V);
  }
  float ev[3] = {Bm[0][0], Bm[1][1], Bm[2][2]};
  CSWAP(0, 1)
  CSWAP(1, 2)
  CSWAP(0, 1)  // columns of V sorted by descending eigenvalue

  // U columns: U0 = H V0 / |.|, U1 = GS(H V1), U2 = U0 x U1 (det U = +1)
  float U[3][3];
  float w0[3], w1[3];
#pragma unroll
  for (int i = 0; i < 3; ++i)
    w0[i] = H[i][0] * V[0][0] + H[i][1] * V[1][0] + H[i][2] * V[2][0];
  float n0 = sqrtf(w0[0] * w0[0] + w0[1] * w0[1] + w0[2] * w0[2]);
  float in0 = (n0 > 1e-20f) ? 1.0f / n0 : 0.0f;
#pragma unroll
  for (int i = 0; i < 3; ++i) U[i][0] = w0[i] * in0;

#pragma unroll
  for (int i = 0; i < 3; ++i)
    w1[i] = H[i][0] * V[0][1] + H[i][1] * V[1][1] + H[i][2] * V[2][1];
  float d01 = U[0][0] * w1[0] + U[1][0] * w1[1] + U[2][0] * w1[2];
#pragma unroll
  for (int i = 0; i < 3; ++i) w1[i] -= d01 * U[i][0];
  float n1 = sqrtf(w1[0] * w1[0] + w1[1] * w1[1] + w1[2] * w1[2]);
  float in1 = (n1 > 1e-20f) ? 1.0f / n1 : 0.0f;
#pragma unroll
  for (int i = 0; i < 3; ++i) U[i][1] = w1[i] * in1;

  U[0][2] = U[1][0] * U[2][1] - U[2][0] * U[1][1];
  U[1][2] = U[2][0] * U[0][1] - U[0][0] * U[2][1];
  U[2][2] = U[0][0] * U[1][1] - U[1][0] * U[0][1];

  float detV = V[0][0] * (V[1][1] * V[2][2] - V[1][2] * V[2][1]) -
               V[0][1] * (V[1][0] * V[2][2] - V[1][2] * V[2][0]) +
               V[0][2] * (V[1][0] * V[2][1] - V[1][1] * V[2][0]);
  float s3 = (detV >= 0.0f) ? 1.0f : -1.0f;

  // R = V diag(1,1,s) U^T (invariant to eigencolumn sign choices)
  float R[3][3];
#pragma unroll
  for (int i = 0; i < 3; ++i)
#pragma unroll
    for (int j = 0; j < 3; ++j)
      R[i][j] = V[i][0] * U[j][0] + V[i][1] * U[j][1] + s3 * V[i][2] * U[j][2];

  float tr[3];
#pragma unroll
  for (int i = 0; i < 3; ++i)
    tr[i] = tc[i] - (R[i][0] * sc[0] + R[i][1] * sc[1] + R[i][2] * sc[2]);

  float4* o4 = (float4*)o;
  o4[0] = make_float4(R[0][0], R[0][1], R[0][2], tr[0]);
  o4[1] = make_float4(R[1][0], R[1][1], R[1][2], tr[1]);
  o4[2] = make_float4(R[2][0], R[2][1], R[2][2], tr[2]);
  o4[3] = make_float4(0.0f, 0.0f, 0.0f, 1.0f);
}

// R2 skeleton (proven 70.9 us): contiguous stride-TPB float4 staging,
// interleaved point ownership p = t + i*256 with conflict-free scalar
// LDS reads (stride 12B across lanes -> 2 lanes/bank = free), fused SVD.
// Deltas vs R2: (1) weights via 4 scalar coalesced GLOBAL loads matching
// interleaved ownership (sh_w dropped: -4KB LDS -> 6 blocks/CU);
// (2) reduction = 2 shuffle levels + LDS transpose (96+96 -> 32+32 ops),
// partial buffer aliased over sh_src behind a barrier;
// (3) NO __launch_bounds__ min-waves hint (R8's SGPR-112 suspect).
__global__ __launch_bounds__(TPB) void wproc_fused(
    const float* __restrict__ src, const float* __restrict__ tgt,
    const float* __restrict__ wts, float* __restrict__ out) {
  const int b = blockIdx.x;
  const int t = threadIdx.x;
  const int lane = t & 63, wave = t >> 6;

  __shared__ float4 sh_src[NPTS * 3 / 4];  // 12 KiB
  __shared__ float4 sh_tgt[NPTS * 3 / 4];  // 12 KiB
  __shared__ float sh_fin[4][17];
  __shared__ float sh_r[16];
  // Partial-sum matrix aliased over sh_src's first 5 KiB; only written
  // after a barrier proving all sh_src reads completed.
  float(*sh_part)[20] = (float(*)[20])sh_src;  // 64 rows x 20 floats

  const float4* g_src = (const float4*)(src + (size_t)b * (NPTS * 3));
  const float4* g_tgt = (const float4*)(tgt + (size_t)b * (NPTS * 3));
  const float* g_w = wts + (size_t)b * NPTS;

  // ---- Coalesced stage (R2 pattern: 64 consecutive float4 per wave) ----
#pragma unroll
  for (int i = 0; i < 3; ++i) {
    sh_src[t + i * TPB] = g_src[t + i * TPB];
    sh_tgt[t + i * TPB] = g_tgt[t + i * TPB];
  }
  // Weights direct-to-register: 4 scalar coalesced loads (4B stride).
  const float wv0 = g_w[t], wv1 = g_w[t + 256], wv2 = g_w[t + 512],
              wv3 = g_w[t + 768];
  __syncthreads();

  const float* ss = (const float*)sh_src;
  const float* st = (const float*)sh_tgt;

  // acc: [0]=Sw, [1..3]=Σw*src, [4..6]=Σw*tgt, [7..15]=Σw*src⊗tgt
  float acc[16];
#pragma unroll
  for (int k = 0; k < 16; ++k) acc[k] = 0.0f;

  const float wreg[4] = {wv0, wv1, wv2, wv3};
#pragma unroll
  for (int i = 0; i < 4; ++i) {
    const int p = t + i * TPB;  // interleaved ownership: matches wreg[i]
    float wv = fmaxf(wreg[i], 0.0f);  // WEIGHT_THRESH = 0.0
    const float sx = ss[3 * p + 0], sy = ss[3 * p + 1], sz = ss[3 * p + 2];
    const float tx = st[3 * p + 0], ty = st[3 * p + 1], tz = st[3 * p + 2];
    const float wsx = wv * sx, wsy = wv * sy, wsz = wv * sz;
    acc[0] += wv;
    acc[1] += wsx;      acc[2] += wsy;      acc[3] += wsz;
    acc[4] += wv * tx;  acc[5] += wv * ty;  acc[6] += wv * tz;
    acc[7]  += wsx * tx; acc[8]  += wsx * ty; acc[9]  += wsx * tz;
    acc[10] += wsy * tx; acc[11] += wsy * ty; acc[12] += wsy * tz;
    acc[13] += wsz * tx; acc[14] += wsz * ty; acc[15] += wsz * tz;
  }

  // ---- Reduction: 2 shuffle levels, then LDS transpose ----
#pragma unroll
  for (int k = 0; k < 16; ++k) acc[k] += __shfl_down(acc[k], 32, 64);
#pragma unroll
  for (int k = 0; k < 16; ++k) acc[k] += __shfl_down(acc[k], 16, 64);

  __syncthreads();  // all sh_src reads done -> safe to alias as sh_part

  if (lane < 16) {  // lanes 0..15 hold sums over their 4-lane comb
    float4* pr = (float4*)&sh_part[wave * 16 + lane][0];
    pr[0] = make_float4(acc[0], acc[1], acc[2], acc[3]);
    pr[1] = make_float4(acc[4], acc[5], acc[6], acc[7]);
    pr[2] = make_float4(acc[8], acc[9], acc[10], acc[11]);
    pr[3] = make_float4(acc[12], acc[13], acc[14], acc[15]);
  }
  __syncthreads();

  // 64 threads: thread (g,k) sums component k over rows g*16..g*16+15.
  if (t < 64) {
    const int k = t & 15, g = t >> 4;
    float s = 0.0f;
#pragma unroll
    for (int j = 0; j < 16; ++j) s += sh_part[g * 16 + j][k];
    sh_fin[g][k] = s;
  }
  __syncthreads();

  if (t < 16)
    sh_r[t] = sh_fin[0][t] + sh_fin[1][t] + sh_fin[2][t] + sh_fin[3][t];
  __syncthreads();

  if (t != 0) return;
  float r[16];
#pragma unroll
  for (int k = 0; k < 16; ++k) r[k] = sh_r[k];
  svd_tail_write(r, out + (size_t)b * 16);
}

extern "C" void kernel_launch(void* const* d_in, const int* in_sizes, int n_in,
                              void* d_out, int out_size, void* d_ws, size_t ws_size,
                              hipStream_t stream) {
  const float* src = (const float*)d_in[0];
  const float* tgt = (const float*)d_in[1];
  const float* wts = (const float*)d_in[2];
  float* out = (float*)d_out;
  const int B = in_sizes[0] / (NPTS * 3);
  wproc_fused<<<dim3(B), dim3(TPB), 0, stream>>>(src, tgt, wts, out);
}

// Round 12
// 242.759 us; speedup vs baseline: 1.0079x; 1.0075x over previous
//
#include <hip/hip_runtime.h>
#include <math.h>

#define TPB 256
#define NPTS 1024
#define NB 4  // batches per persistent block

template<int P, int Q, int R>
__device__ __forceinline__ void jrot(float a[3][3], float V[3][3]) {
  float apq = a[P][Q];
  if (fabsf(apq) < 1e-30f) return;
  float theta = (a[Q][Q] - a[P][P]) / (2.0f * apq);
  float t = copysignf(1.0f, theta) / (fabsf(theta) + sqrtf(theta * theta + 1.0f));
  float c = 1.0f / sqrtf(t * t + 1.0f);
  float s = t * c;
  float app = a[P][P], aqq = a[Q][Q];
  a[P][P] = app - t * apq;
  a[Q][Q] = aqq + t * apq;
  a[P][Q] = 0.0f; a[Q][P] = 0.0f;
  float arp = a[R][P], arq = a[R][Q];
  a[R][P] = c * arp - s * arq; a[P][R] = a[R][P];
  a[R][Q] = s * arp + c * arq; a[Q][R] = a[R][Q];
#pragma unroll
  for (int i = 0; i < 3; ++i) {
    float vip = V[i][P], viq = V[i][Q];
    V[i][P] = c * vip - s * viq;
    V[i][Q] = s * vip + c * viq;
  }
}

#define CSWAP(I, J)                                                        \
  if (ev[I] < ev[J]) {                                                     \
    float e_ = ev[I]; ev[I] = ev[J]; ev[J] = e_;                           \
    _Pragma("unroll")                                                      \
    for (int r2_ = 0; r2_ < 3; ++r2_) {                                    \
      float v_ = V[r2_][I]; V[r2_][I] = V[r2_][J]; V[r2_][J] = v_;         \
    }                                                                      \
  }

__device__ __forceinline__ void svd_tail_write(const float r[16], float* o) {
  const float S = r[0];
  const float inv = 1.0f / (S + 1e-5f);
  const float sc[3] = {r[1] * inv, r[2] * inv, r[3] * inv};
  const float tc[3] = {r[4] * inv, r[5] * inv, r[6] * inv};
  const float f = 2.0f - S * inv;

  float H[3][3];
#pragma unroll
  for (int c = 0; c < 3; ++c)
#pragma unroll
    for (int d = 0; d < 3; ++d)
      H[c][d] = r[7 + 3 * c + d] * inv - sc[c] * tc[d] * f;

  float Bm[3][3];
#pragma unroll
  for (int i = 0; i < 3; ++i)
#pragma unroll
    for (int j = 0; j < 3; ++j)
      Bm[i][j] = H[0][i] * H[0][j] + H[1][i] * H[1][j] + H[2][i] * H[2][j];

  float V[3][3] = {{1, 0, 0}, {0, 1, 0}, {0, 0, 1}};
  for (int sweep = 0; sweep < 8; ++sweep) {
    jrot<0, 1, 2>(Bm, V);
    jrot<0, 2, 1>(Bm, V);
    jrot<1, 2, 0>(Bm, V);
  }
  float ev[3] = {Bm[0][0], Bm[1][1], Bm[2][2]};
  CSWAP(0, 1)
  CSWAP(1, 2)
  CSWAP(0, 1)

  float U[3][3];
  float w0[3], w1[3];
#pragma unroll
  for (int i = 0; i < 3; ++i)
    w0[i] = H[i][0] * V[0][0] + H[i][1] * V[1][0] + H[i][2] * V[2][0];
  float n0 = sqrtf(w0[0] * w0[0] + w0[1] * w0[1] + w0[2] * w0[2]);
  float in0 = (n0 > 1e-20f) ? 1.0f / n0 : 0.0f;
#pragma unroll
  for (int i = 0; i < 3; ++i) U[i][0] = w0[i] * in0;

#pragma unroll
  for (int i = 0; i < 3; ++i)
    w1[i] = H[i][0] * V[0][1] + H[i][1] * V[1][1] + H[i][2] * V[2][1];
  float d01 = U[0][0] * w1[0] + U[1][0] * w1[1] + U[2][0] * w1[2];
#pragma unroll
  for (int i = 0; i < 3; ++i) w1[i] -= d01 * U[i][0];
  float n1 = sqrtf(w1[0] * w1[0] + w1[1] * w1[1] + w1[2] * w1[2]);
  float in1 = (n1 > 1e-20f) ? 1.0f / n1 : 0.0f;
#pragma unroll
  for (int i = 0; i < 3; ++i) U[i][1] = w1[i] * in1;

  U[0][2] = U[1][0] * U[2][1] - U[2][0] * U[1][1];
  U[1][2] = U[2][0] * U[0][1] - U[0][0] * U[2][1];
  U[2][2] = U[0][0] * U[1][1] - U[1][0] * U[0][1];

  float detV = V[0][0] * (V[1][1] * V[2][2] - V[1][2] * V[2][1]) -
               V[0][1] * (V[1][0] * V[2][2] - V[1][2] * V[2][0]) +
               V[0][2] * (V[1][0] * V[2][1] - V[1][1] * V[2][0]);
  float s3 = (detV >= 0.0f) ? 1.0f : -1.0f;

  float R[3][3];
#pragma unroll
  for (int i = 0; i < 3; ++i)
#pragma unroll
    for (int j = 0; j < 3; ++j)
      R[i][j] = V[i][0] * U[j][0] + V[i][1] * U[j][1] + s3 * V[i][2] * U[j][2];

  float tr[3];
#pragma unroll
  for (int i = 0; i < 3; ++i)
    tr[i] = tc[i] - (R[i][0] * sc[0] + R[i][1] * sc[1] + R[i][2] * sc[2]);

  float4* o4 = (float4*)o;
  o4[0] = make_float4(R[0][0], R[0][1], R[0][2], tr[0]);
  o4[1] = make_float4(R[1][0], R[1][1], R[1][2], tr[1]);
  o4[2] = make_float4(R[2][0], R[2][1], R[2][2], tr[2]);
  o4[3] = make_float4(0.0f, 0.0f, 0.0f, 1.0f);
}

#define PT(W, SX, SY, SZ, TX, TY, TZ)                                   \
  {                                                                     \
    float wv = fmaxf((W), 0.0f); /* WEIGHT_THRESH = 0.0 */              \
    float wsx = wv * (SX), wsy = wv * (SY), wsz = wv * (SZ);            \
    acc[0] += wv;                                                       \
    acc[1] += wsx;       acc[2] += wsy;       acc[3] += wsz;            \
    acc[4] += wv * (TX); acc[5] += wv * (TY); acc[6] += wv * (TZ);      \
    acc[7]  += wsx * (TX); acc[8]  += wsx * (TY); acc[9]  += wsx * (TZ);\
    acc[10] += wsy * (TX); acc[11] += wsy * (TY); acc[12] += wsy * (TZ);\
    acc[13] += wsz * (TX); acc[14] += wsz * (TY); acc[15] += wsz * (TZ);\
  }

// Persistent pipelined streaming kernel: each block reduces NB batches,
// prefetching batch j+1 into registers while reducing batch j. Keeps a
// full 28 KB/block continuously in flight (one-shot blocks idle their
// memory pipe ~75% of block lifetime -> measured 2.5 TB/s ceiling
// across R7/R8/R9). No SVD tail here (split kernel).
__global__ __launch_bounds__(TPB) void wproc_pipe(
    const float* __restrict__ src, const float* __restrict__ tgt,
    const float* __restrict__ wts, float* __restrict__ ws, int nbat) {
  const int t = threadIdx.x;
  const int lane = t & 63, wave = t >> 6;
  const int gsz = gridDim.x;

  __shared__ float sh_part[64][20];  // 5.0 KiB, stride-20 rows
  __shared__ float sh_fin[4][17];

  float4 cs0, cs1, cs2, cu0, cu1, cu2, cw;
  float4 ns0, ns1, ns2, nu0, nu1, nu2, nw;

  {  // prologue: batch for j=0
    const size_t b0 = blockIdx.x;
    if ((int)b0 < nbat) {
      const float4* gs = (const float4*)(src + b0 * (NPTS * 3));
      const float4* gt = (const float4*)(tgt + b0 * (NPTS * 3));
      const float4* gw = (const float4*)(wts + b0 * NPTS);
      cs0 = gs[3 * t + 0]; cs1 = gs[3 * t + 1]; cs2 = gs[3 * t + 2];
      cu0 = gt[3 * t + 0]; cu1 = gt[3 * t + 1]; cu2 = gt[3 * t + 2];
      cw = gw[t];
    }
  }

#pragma unroll
  for (int j = 0; j < NB; ++j) {
    // ---- prefetch batch j+1 (issued before any barrier of batch j) ----
    if (j + 1 < NB) {
      const size_t bn = (size_t)blockIdx.x + (size_t)(j + 1) * gsz;
      if ((int)bn < nbat) {
        const float4* gs = (const float4*)(src + bn * (NPTS * 3));
        const float4* gt = (const float4*)(tgt + bn * (NPTS * 3));
        const float4* gw = (const float4*)(wts + bn * NPTS);
        ns0 = gs[3 * t + 0]; ns1 = gs[3 * t + 1]; ns2 = gs[3 * t + 2];
        nu0 = gt[3 * t + 0]; nu1 = gt[3 * t + 1]; nu2 = gt[3 * t + 2];
        nw = gw[t];
      }
    }

    const size_t bc = (size_t)blockIdx.x + (size_t)j * gsz;
    const bool valid = (int)bc < nbat;

    // ---- reduce current batch from registers ----
    float acc[16];
#pragma unroll
    for (int k = 0; k < 16; ++k) acc[k] = 0.0f;
    if (valid) {
      PT(cw.x, cs0.x, cs0.y, cs0.z, cu0.x, cu0.y, cu0.z)
      PT(cw.y, cs0.w, cs1.x, cs1.y, cu0.w, cu1.x, cu1.y)
      PT(cw.z, cs1.z, cs1.w, cs2.x, cu1.z, cu1.w, cu2.x)
      PT(cw.w, cs2.y, cs2.z, cs2.w, cu2.y, cu2.z, cu2.w)
    }

#pragma unroll
    for (int k = 0; k < 16; ++k) acc[k] += __shfl_down(acc[k], 32, 64);
#pragma unroll
    for (int k = 0; k < 16; ++k) acc[k] += __shfl_down(acc[k], 16, 64);

    if (lane < 16) {
      float4* pr = (float4*)&sh_part[wave * 16 + lane][0];
      pr[0] = make_float4(acc[0], acc[1], acc[2], acc[3]);
      pr[1] = make_float4(acc[4], acc[5], acc[6], acc[7]);
      pr[2] = make_float4(acc[8], acc[9], acc[10], acc[11]);
      pr[3] = make_float4(acc[12], acc[13], acc[14], acc[15]);
    }
    __syncthreads();

    if (t < 64) {
      const int k = t & 15, g = t >> 4;
      float s = 0.0f;
#pragma unroll
      for (int jj = 0; jj < 16; ++jj) s += sh_part[g * 16 + jj][k];
      sh_fin[g][k] = s;
    }
    __syncthreads();

    if (t < 16 && valid)
      ws[bc * 16 + t] =
          sh_fin[0][t] + sh_fin[1][t] + sh_fin[2][t] + sh_fin[3][t];
    __syncthreads();  // protect sh_part/sh_fin reuse next iteration

    // rotate pipeline registers (dead on last iteration)
    cs0 = ns0; cs1 = ns1; cs2 = ns2;
    cu0 = nu0; cu1 = nu1; cu2 = nu2;
    cw = nw;
  }
}

// One thread per batch: fully parallel 3x3 SVD + transform assembly.
__global__ __launch_bounds__(TPB) void wproc_svd(
    const float* __restrict__ ws, float* __restrict__ out, int B) {
  const int i = blockIdx.x * TPB + threadIdx.x;
  if (i >= B) return;
  const float4* p = (const float4*)(ws + (size_t)i * 16);
  const float4 a = p[0], bq = p[1], c = p[2], d = p[3];
  const float r[16] = {a.x,  a.y,  a.z,  a.w,  bq.x, bq.y, bq.z, bq.w,
                       c.x,  c.y,  c.z,  c.w,  d.x,  d.y,  d.z,  d.w};
  svd_tail_write(r, out + (size_t)i * 16);
}

// Fallback (ws too small): R9 fused kernel, verified absmax 3.9e-3.
__global__ __launch_bounds__(TPB) void wproc_fused(
    const float* __restrict__ src, const float* __restrict__ tgt,
    const float* __restrict__ wts, float* __restrict__ out) {
  const int b = blockIdx.x;
  const int t = threadIdx.x;
  const int lane = t & 63, wave = t >> 6;

  __shared__ float4 sh_src[NPTS * 3 / 4];
  __shared__ float4 sh_tgt[NPTS * 3 / 4];
  __shared__ float sh_fin[4][17];
  __shared__ float sh_r[16];
  float(*sh_part)[20] = (float(*)[20])sh_src;

  const float4* g_src = (const float4*)(src + (size_t)b * (NPTS * 3));
  const float4* g_tgt = (const float4*)(tgt + (size_t)b * (NPTS * 3));
  const float* g_w = wts + (size_t)b * NPTS;

#pragma unroll
  for (int i = 0; i < 3; ++i) {
    sh_src[t + i * TPB] = g_src[t + i * TPB];
    sh_tgt[t + i * TPB] = g_tgt[t + i * TPB];
  }
  const float wv0 = g_w[t], wv1 = g_w[t + 256], wv2 = g_w[t + 512],
              wv3 = g_w[t + 768];
  __syncthreads();

  const float* ss = (const float*)sh_src;
  const float* st = (const float*)sh_tgt;

  float acc[16];
#pragma unroll
  for (int k = 0; k < 16; ++k) acc[k] = 0.0f;

  const float wreg[4] = {wv0, wv1, wv2, wv3};
#pragma unroll
  for (int i = 0; i < 4; ++i) {
    const int p = t + i * TPB;
    float wv = fmaxf(wreg[i], 0.0f);
    const float sx = ss[3 * p + 0], sy = ss[3 * p + 1], sz = ss[3 * p + 2];
    const float tx = st[3 * p + 0], ty = st[3 * p + 1], tz = st[3 * p + 2];
    const float wsx = wv * sx, wsy = wv * sy, wsz = wv * sz;
    acc[0] += wv;
    acc[1] += wsx;      acc[2] += wsy;      acc[3] += wsz;
    acc[4] += wv * tx;  acc[5] += wv * ty;  acc[6] += wv * tz;
    acc[7]  += wsx * tx; acc[8]  += wsx * ty; acc[9]  += wsx * tz;
    acc[10] += wsy * tx; acc[11] += wsy * ty; acc[12] += wsy * tz;
    acc[13] += wsz * tx; acc[14] += wsz * ty; acc[15] += wsz * tz;
  }

#pragma unroll
  for (int k = 0; k < 16; ++k) acc[k] += __shfl_down(acc[k], 32, 64);
#pragma unroll
  for (int k = 0; k < 16; ++k) acc[k] += __shfl_down(acc[k], 16, 64);

  __syncthreads();

  if (lane < 16) {
    float4* pr = (float4*)&sh_part[wave * 16 + lane][0];
    pr[0] = make_float4(acc[0], acc[1], acc[2], acc[3]);
    pr[1] = make_float4(acc[4], acc[5], acc[6], acc[7]);
    pr[2] = make_float4(acc[8], acc[9], acc[10], acc[11]);
    pr[3] = make_float4(acc[12], acc[13], acc[14], acc[15]);
  }
  __syncthreads();

  if (t < 64) {
    const int k = t & 15, g = t >> 4;
    float s = 0.0f;
#pragma unroll
    for (int jj = 0; jj < 16; ++jj) s += sh_part[g * 16 + jj][k];
    sh_fin[g][k] = s;
  }
  __syncthreads();

  if (t < 16)
    sh_r[t] = sh_fin[0][t] + sh_fin[1][t] + sh_fin[2][t] + sh_fin[3][t];
  __syncthreads();

  if (t != 0) return;
  float r[16];
#pragma unroll
  for (int k = 0; k < 16; ++k) r[k] = sh_r[k];
  svd_tail_write(r, out + (size_t)b * 16);
}

extern "C" void kernel_launch(void* const* d_in, const int* in_sizes, int n_in,
                              void* d_out, int out_size, void* d_ws, size_t ws_size,
                              hipStream_t stream) {
  const float* src = (const float*)d_in[0];
  const float* tgt = (const float*)d_in[1];
  const float* wts = (const float*)d_in[2];
  float* out = (float*)d_out;
  const int B = in_sizes[0] / (NPTS * 3);
  const size_t need = (size_t)B * 16 * sizeof(float);
  if (ws_size >= need) {
    const int grid = (B + NB - 1) / NB;  // 2048 persistent blocks
    wproc_pipe<<<dim3(grid), dim3(TPB), 0, stream>>>(src, tgt, wts,
                                                     (float*)d_ws, B);
    wproc_svd<<<dim3((B + TPB - 1) / TPB), dim3(TPB), 0, stream>>>(
        (const float*)d_ws, out, B);
  } else {
    wproc_fused<<<dim3(B), dim3(TPB), 0, stream>>>(src, tgt, wts, out);
  }
}

// Round 13
// 241.631 us; speedup vs baseline: 1.0126x; 1.0047x over previous
//
#include <hip/hip_runtime.h>
#include <math.h>

#define TPB 256
#define NPTS 1024

// One Jacobi rotation on symmetric 3x3 'a' (zeroing a[P][Q]), accumulating
// eigenvectors into columns of V. All indices template-constant so the
// matrices live entirely in registers (no scratch).
template<int P, int Q, int R>
__device__ __forceinline__ void jrot(float a[3][3], float V[3][3]) {
  float apq = a[P][Q];
  if (fabsf(apq) < 1e-30f) return;
  float theta = (a[Q][Q] - a[P][P]) / (2.0f * apq);
  float t = copysignf(1.0f, theta) / (fabsf(theta) + sqrtf(theta * theta + 1.0f));
  float c = 1.0f / sqrtf(t * t + 1.0f);
  float s = t * c;
  float app = a[P][P], aqq = a[Q][Q];
  a[P][P] = app - t * apq;
  a[Q][Q] = aqq + t * apq;
  a[P][Q] = 0.0f; a[Q][P] = 0.0f;
  float arp = a[R][P], arq = a[R][Q];
  a[R][P] = c * arp - s * arq; a[P][R] = a[R][P];
  a[R][Q] = s * arp + c * arq; a[Q][R] = a[R][Q];
#pragma unroll
  for (int i = 0; i < 3; ++i) {
    float vip = V[i][P], viq = V[i][Q];
    V[i][P] = c * vip - s * viq;
    V[i][Q] = s * vip + c * viq;
  }
}

#define CSWAP(I, J)                                                        \
  if (ev[I] < ev[J]) {                                                     \
    float e_ = ev[I]; ev[I] = ev[J]; ev[J] = e_;                           \
    _Pragma("unroll")                                                      \
    for (int r2_ = 0; r2_ < 3; ++r2_) {                                    \
      float v_ = V[r2_][I]; V[r2_][I] = V[r2_][J]; V[r2_][J] = v_;         \
    }                                                                      \
  }

__global__ __launch_bounds__(TPB) void wproc_kernel(
    const float* __restrict__ src, const float* __restrict__ tgt,
    const float* __restrict__ wts, float* __restrict__ out) {
  const int b = blockIdx.x;
  const int t = threadIdx.x;

  __shared__ float4 sh_src[NPTS * 3 / 4];  // 12 KiB
  __shared__ float4 sh_tgt[NPTS * 3 / 4];  // 12 KiB
  __shared__ float4 sh_w[NPTS / 4];        // 4 KiB
  __shared__ float sh_red[4][16];

  // ---- Stage batch into LDS with fully-coalesced float4 loads ----
  const float4* g_src = (const float4*)(src + (size_t)b * (NPTS * 3));
  const float4* g_tgt = (const float4*)(tgt + (size_t)b * (NPTS * 3));
  const float4* g_w   = (const float4*)(wts + (size_t)b * NPTS);
#pragma unroll
  for (int i = 0; i < 3; ++i) {
    sh_src[t + i * TPB] = g_src[t + i * TPB];
    sh_tgt[t + i * TPB] = g_tgt[t + i * TPB];
  }
  sh_w[t] = g_w[t];
  __syncthreads();

  const float* ss = (const float*)sh_src;
  const float* st = (const float*)sh_tgt;
  const float* sw = (const float*)sh_w;

  // ---- Per-thread partial sums over 4 points ----
  // acc: [0]=Sw, [1..3]=Sum w*src, [4..6]=Sum w*tgt, [7..15]=Sum w*src⊗tgt
  float acc[16];
#pragma unroll
  for (int k = 0; k < 16; ++k) acc[k] = 0.0f;

#pragma unroll
  for (int i = 0; i < 4; ++i) {
    const int p = t + i * TPB;
    float wv = sw[p];
    wv = (wv < 0.0f) ? 0.0f : wv;  // WEIGHT_THRESH = 0.0
    const float sx = ss[3 * p + 0], sy = ss[3 * p + 1], sz = ss[3 * p + 2];
    const float tx = st[3 * p + 0], ty = st[3 * p + 1], tz = st[3 * p + 2];
    const float wsx = wv * sx, wsy = wv * sy, wsz = wv * sz;
    acc[0] += wv;
    acc[1] += wsx;      acc[2] += wsy;      acc[3] += wsz;
    acc[4] += wv * tx;  acc[5] += wv * ty;  acc[6] += wv * tz;
    acc[7]  += wsx * tx; acc[8]  += wsx * ty; acc[9]  += wsx * tz;
    acc[10] += wsy * tx; acc[11] += wsy * ty; acc[12] += wsy * tz;
    acc[13] += wsz * tx; acc[14] += wsz * ty; acc[15] += wsz * tz;
  }

  // ---- Wave (64-lane) shuffle reduction, then cross-wave via LDS ----
#pragma unroll
  for (int off = 32; off >= 1; off >>= 1) {
#pragma unroll
    for (int k = 0; k < 16; ++k) acc[k] += __shfl_down(acc[k], off, 64);
  }
  const int wave = t >> 6;
  if ((t & 63) == 0) {
#pragma unroll
    for (int k = 0; k < 16; ++k) sh_red[wave][k] = acc[k];
  }
  __syncthreads();
  if (t != 0) return;

  float r[16];
#pragma unroll
  for (int k = 0; k < 16; ++k)
    r[k] = sh_red[0][k] + sh_red[1][k] + sh_red[2][k] + sh_red[3][k];

  // ---- Centroids and covariance H (single-pass algebra) ----
  const float S = r[0];
  const float inv = 1.0f / (S + 1e-5f);
  const float sc[3] = {r[1] * inv, r[2] * inv, r[3] * inv};
  const float tc[3] = {r[4] * inv, r[5] * inv, r[6] * inv};
  const float f = 2.0f - S * inv;  // exact eps correction factor

  float H[3][3];
#pragma unroll
  for (int c = 0; c < 3; ++c)
#pragma unroll
    for (int d = 0; d < 3; ++d)
      H[c][d] = r[7 + 3 * c + d] * inv - sc[c] * tc[d] * f;

  // ---- 3x3 SVD via Jacobi eigendecomposition of H^T H ----
  float Bm[3][3];
#pragma unroll
  for (int i = 0; i < 3; ++i)
#pragma unroll
    for (int j = 0; j < 3; ++j)
      Bm[i][j] = H[0][i] * H[0][j] + H[1][i] * H[1][j] + H[2][i] * H[2][j];

  float V[3][3] = {{1, 0, 0}, {0, 1, 0}, {0, 0, 1}};
  for (int sweep = 0; sweep < 8; ++sweep) {
    jrot<0, 1, 2>(Bm, V);
    jrot<0, 2, 1>(Bm, V);
    jrot<1, 2, 0>(Bm, V);
  }
  float ev[3] = {Bm[0][0], Bm[1][1], Bm[2][2]};
  CSWAP(0, 1)
  CSWAP(1, 2)
  CSWAP(0, 1)  // columns of V now sorted by descending eigenvalue

  // U columns: U0 = H V0 / |.|, U1 = GS(H V1), U2 = U0 x U1 (det U = +1)
  float U[3][3];
  float w0[3], w1[3];
#pragma unroll
  for (int i = 0; i < 3; ++i)
    w0[i] = H[i][0] * V[0][0] + H[i][1] * V[1][0] + H[i][2] * V[2][0];
  float n0 = sqrtf(w0[0] * w0[0] + w0[1] * w0[1] + w0[2] * w0[2]);
  float in0 = (n0 > 1e-20f) ? 1.0f / n0 : 0.0f;
#pragma unroll
  for (int i = 0; i < 3; ++i) U[i][0] = w0[i] * in0;

#pragma unroll
  for (int i = 0; i < 3; ++i)
    w1[i] = H[i][0] * V[0][1] + H[i][1] * V[1][1] + H[i][2] * V[2][1];
  float d01 = U[0][0] * w1[0] + U[1][0] * w1[1] + U[2][0] * w1[2];
#pragma unroll
  for (int i = 0; i < 3; ++i) w1[i] -= d01 * U[i][0];
  float n1 = sqrtf(w1[0] * w1[0] + w1[1] * w1[1] + w1[2] * w1[2]);
  float in1 = (n1 > 1e-20f) ? 1.0f / n1 : 0.0f;
#pragma unroll
  for (int i = 0; i < 3; ++i) U[i][1] = w1[i] * in1;

  U[0][2] = U[1][0] * U[2][1] - U[2][0] * U[1][1];
  U[1][2] = U[2][0] * U[0][1] - U[0][0] * U[2][1];
  U[2][2] = U[0][0] * U[1][1] - U[1][0] * U[0][1];

  // s = sign(det V * det U); det U = +1 by construction.
  float detV = V[0][0] * (V[1][1] * V[2][2] - V[1][2] * V[2][1]) -
               V[0][1] * (V[1][0] * V[2][2] - V[1][2] * V[2][0]) +
               V[0][2] * (V[1][0] * V[2][1] - V[1][1] * V[2][0]);
  float s3 = (detV >= 0.0f) ? 1.0f : -1.0f;

  // R = V diag(1,1,s) U^T   (invariant to eigencolumn sign choices)
  float R[3][3];
#pragma unroll
  for (int i = 0; i < 3; ++i)
#pragma unroll
    for (int j = 0; j < 3; ++j)
      R[i][j] = V[i][0] * U[j][0] + V[i][1] * U[j][1] + s3 * V[i][2] * U[j][2];

  float tr[3];
#pragma unroll
  for (int i = 0; i < 3; ++i)
    tr[i] = tc[i] - (R[i][0] * sc[0] + R[i][1] * sc[1] + R[i][2] * sc[2]);

  float* o = out + (size_t)b * 16;
  o[0] = R[0][0]; o[1] = R[0][1]; o[2]  = R[0][2]; o[3]  = tr[0];
  o[4] = R[1][0]; o[5] = R[1][1]; o[6]  = R[1][2]; o[7]  = tr[1];
  o[8] = R[2][0]; o[9] = R[2][1]; o[10] = R[2][2]; o[11] = tr[2];
  o[12] = 0.0f;   o[13] = 0.0f;   o[14] = 0.0f;    o[15] = 1.0f;
}

extern "C" void kernel_launch(void* const* d_in, const int* in_sizes, int n_in,
                              void* d_out, int out_size, void* d_ws, size_t ws_size,
                              hipStream_t stream) {
  const float* src = (const float*)d_in[0];
  const float* tgt = (const float*)d_in[1];
  const float* wts = (const float*)d_in[2];
  float* out = (float*)d_out;
  const int B = in_sizes[0] / (NPTS * 3);
  wproc_kernel<<<dim3(B), dim3(TPB), 0, stream>>>(src, tgt, wts, out);
}